// Round 2
// baseline (242.548 us; speedup 1.0000x reference)
//
#include <hip/hip_runtime.h>
#include <hip/hip_bf16.h>

#define TSC_OUT_LEN 16384
#define TSC_ENC_LEN 16368   // 16384 - 16384/1024
#define TSC_ROWS    4       // batch rows per block — amortizes staging, adds MLP

// out[b,j] = sum_{e=1..10} data[b, off_e + (j>>e)] * weights[(2^e-1) + (j & (2^e-1))]
//            + sum_e bias[e-1],   off_e = OUT_LEN - (OUT_LEN >> (e-1)).
// One thread computes 8 consecutive outputs (j0) for TSC_ROWS rows.
// Weight fragments depend only on j0 -> loaded into registers ONCE per block
// (via LDS, +1 shift makes frag bases 16B-aligned), reused across all rows.
// Per row: float4 (e=1) + float2 (e=2) + 8 scalar (e>=3) coalesced data loads,
// 80 FMAs, two float4 stores. Rows fully unrolled for load-level parallelism.
__global__ __launch_bounds__(256) void tsc_transpose_kernel(
    const float* __restrict__ data,
    const float* __restrict__ weights,
    const float* __restrict__ bias,
    float* __restrict__ out)
{
    __shared__ float wl[2048];
    const int tid = threadIdx.x;
    for (int i = tid; i < 2047; i += 256) wl[i + 1] = weights[i];
    if (tid == 0) wl[0] = 0.0f;
    __syncthreads();

    float bs = 0.0f;
#pragma unroll
    for (int i = 0; i < 10; ++i) bs += bias[i];

    const int tile = (blockIdx.x & 7) << 11;          // which 2048-wide tile
    const int b0   = (int)(blockIdx.x >> 3) * TSC_ROWS; // first batch row
    const int j0   = tile + (tid << 3);               // 8 consecutive outputs

    // ---- weight fragments -> registers (once per block) ----
    const float w1 = wl[2], w2 = wl[3];               // e=1
    const float4 kv2 = *reinterpret_cast<const float4*>(&wl[4]);   // e=2 (j0&3==0)
    float4 kf0[8], kf1[8];                            // e=3..10
#pragma unroll
    for (int e = 3; e <= 10; ++e) {
        const int w  = 1 << e;
        const int kb = w + (j0 & (w - 1));            // 8-aligned thanks to +1 shift
        kf0[e - 3] = *reinterpret_cast<const float4*>(&wl[kb]);
        kf1[e - 3] = *reinterpret_cast<const float4*>(&wl[kb + 4]);
    }

#pragma unroll
    for (int r = 0; r < TSC_ROWS; ++r) {
        const float* drow = data + (size_t)(b0 + r) * TSC_ENC_LEN;

        const float4 d4 = *reinterpret_cast<const float4*>(drow + (j0 >> 1));
        const float2 d2 = *reinterpret_cast<const float2*>(drow + 8192 + (j0 >> 2));
        float c[8];
#pragma unroll
        for (int e = 3; e <= 10; ++e) {
            const int off = TSC_OUT_LEN - (TSC_OUT_LEN >> (e - 1));
            c[e - 3] = drow[off + (j0 >> e)];
        }

        float acc[8];
#pragma unroll
        for (int k = 0; k < 8; ++k) acc[k] = bs;

        acc[0] += d4.x * w1; acc[1] += d4.x * w2;
        acc[2] += d4.y * w1; acc[3] += d4.y * w2;
        acc[4] += d4.z * w1; acc[5] += d4.z * w2;
        acc[6] += d4.w * w1; acc[7] += d4.w * w2;

        acc[0] += d2.x * kv2.x; acc[1] += d2.x * kv2.y;
        acc[2] += d2.x * kv2.z; acc[3] += d2.x * kv2.w;
        acc[4] += d2.y * kv2.x; acc[5] += d2.y * kv2.y;
        acc[6] += d2.y * kv2.z; acc[7] += d2.y * kv2.w;

#pragma unroll
        for (int e = 3; e <= 10; ++e) {
            const float cc = c[e - 3];
            const float4 k0 = kf0[e - 3], k1 = kf1[e - 3];
            acc[0] += cc * k0.x; acc[1] += cc * k0.y;
            acc[2] += cc * k0.z; acc[3] += cc * k0.w;
            acc[4] += cc * k1.x; acc[5] += cc * k1.y;
            acc[6] += cc * k1.z; acc[7] += cc * k1.w;
        }

        float4* o = reinterpret_cast<float4*>(out + (size_t)(b0 + r) * TSC_OUT_LEN + j0);
        o[0] = make_float4(acc[0], acc[1], acc[2], acc[3]);
        o[1] = make_float4(acc[4], acc[5], acc[6], acc[7]);
    }
}

extern "C" void kernel_launch(void* const* d_in, const int* in_sizes, int n_in,
                              void* d_out, int out_size, void* d_ws, size_t ws_size,
                              hipStream_t stream) {
    const float* data    = (const float*)d_in[0];
    const float* weights = (const float*)d_in[1];
    const float* bias    = (const float*)d_in[2];
    float* out = (float*)d_out;

    const int B = in_sizes[0] / TSC_ENC_LEN;          // 2048
    dim3 grid((B / TSC_ROWS) * 8);                    // 8 tiles x 512 row-groups
    dim3 block(256);
    tsc_transpose_kernel<<<grid, block, 0, stream>>>(data, weights, bias, out);
}

// Round 4
// 241.472 us; speedup vs baseline: 1.0045x; 1.0045x over previous
//
#include <hip/hip_runtime.h>
#include <hip/hip_bf16.h>

#define TSC_OUT_LEN 16384
#define TSC_ENC_LEN 16368   // 16384 - 16384/1024

// out[b,j] = sum_{e=1..10} data[b, off_e + (j>>e)] * weights[(2^e-1) + (j&(2^e-1))]
//            + sum_e bias[e-1],  off_e = 16384 - (16384 >> (e-1)).
//
// VMEM-issue-bound (~1 vmem instr/cy/CU cap): minimize vmem instr count.
// Block = 512 threads = half a row (16 outputs/thread, j0 = 8192*t + 16*tid):
//   e=1: 2x float4, e=2: float4, e=3: float2 (16B/instr global reads)
//   e=4..10 coeffs: contiguous 1016-float half-row tail staged to LDS (dwordx4)
//   weights: staged to LDS, +1 shift (16B-aligned frags) + CUMULATIVE pad
//   swz(g) = g + 4*(g>>4)  — bijective (monotone), frags stay contiguous;
//   bank analysis: e<=8 conflict-free/2-way, e=9 4-way, e=10 8-way.
//   stores: 4x float4.

__device__ __forceinline__ int swz(int g) { return g + 4 * (g >> 4); }

__global__ __launch_bounds__(512) void tsc_transpose_kernel(
    const float* __restrict__ data,
    const float* __restrict__ weights,
    const float* __restrict__ bias,
    float* __restrict__ out)
{
    __shared__ __align__(16) float wl[2560];  // swz(2047) = 2555
    __shared__ __align__(16) float dl[1024];  // e=4..10 data tail for this half-row

    const int tid = threadIdx.x;
    const int t   = blockIdx.x & 1;           // half-row tile
    const int b   = blockIdx.x >> 1;          // batch row
    const float* drow = data + (size_t)b * TSC_ENC_LEN;

    // ---- stage weights (2047 floats), +1 shift, swizzled ----
    if (tid < 511) {
        const float4 w4 = *reinterpret_cast<const float4*>(weights + 4 * tid);
        const int g = 4 * tid + 1;
        wl[swz(g)]     = w4.x;
        wl[swz(g + 1)] = w4.y;
        wl[swz(g + 2)] = w4.z;
        wl[swz(g + 3)] = w4.w;
    } else {
        wl[swz(2045)] = weights[2044];
        wl[swz(2046)] = weights[2045];
        wl[swz(2047)] = weights[2046];
    }

    // ---- stage e=4..10 data tail (7 chunks, 1016 floats, 254 dwordx4) ----
    if (tid < 254) {
        // chunk c (e = c+4): q = tid - (256 - (256>>c))
        const int c = (tid >= 128) + (tid >= 192) + (tid >= 224) +
                      (tid >= 240) + (tid >= 248) + (tid >= 252);
        const int q   = tid - (256 - (256 >> c));
        const int src = 16384 - (2048 >> c) + t * (512 >> c) + 4 * q;
        const int dst = 1024 - (1024 >> c) + 4 * q;
        const float4 v = *reinterpret_cast<const float4*>(drow + src);
        *reinterpret_cast<float4*>(&dl[dst]) = v;
    }
    __syncthreads();

    float bs = bias[0] + bias[1] + bias[2] + bias[3] + bias[4] +
               bias[5] + bias[6] + bias[7] + bias[8] + bias[9];

    const int j0 = t * 8192 + tid * 16;

    // ---- global coefficient loads (e=1..3), 16B vectorized ----
    const float4 d1a = *reinterpret_cast<const float4*>(drow + t * 4096 + 8 * tid);
    const float4 d1b = *reinterpret_cast<const float4*>(drow + t * 4096 + 8 * tid + 4);
    const float4 d2  = *reinterpret_cast<const float4*>(drow + 8192 + t * 2048 + 4 * tid);
    const float2 d3  = *reinterpret_cast<const float2*>(drow + 12288 + t * 1024 + 2 * tid);

    // ---- e=4..10 coefficients from LDS (stride-1 / broadcast: conflict-free) ----
    float cds[7];
    cds[0] = dl[tid];                  // e=4
    cds[1] = dl[512  + (tid >> 1)];    // e=5
    cds[2] = dl[768  + (tid >> 2)];    // e=6
    cds[3] = dl[896  + (tid >> 3)];    // e=7
    cds[4] = dl[960  + (tid >> 4)];    // e=8
    cds[5] = dl[992  + (tid >> 5)];    // e=9
    cds[6] = dl[1008 + (tid >> 6)];    // e=10

    float acc[16];

    // e=1: weights g=2,3 (swz identity below 16)
    {
        const float w1 = wl[2], w2 = wl[3];
        const float d1[8] = {d1a.x, d1a.y, d1a.z, d1a.w, d1b.x, d1b.y, d1b.z, d1b.w};
#pragma unroll
        for (int k = 0; k < 16; ++k)
            acc[k] = bs + d1[k >> 1] * ((k & 1) ? w2 : w1);
    }
    // e=2: frag g=[4,8) uniform
    {
        const float4 kf = *reinterpret_cast<const float4*>(&wl[4]);
        const float kw[4] = {kf.x, kf.y, kf.z, kf.w};
        const float dd[4] = {d2.x, d2.y, d2.z, d2.w};
#pragma unroll
        for (int k = 0; k < 16; ++k)
            acc[k] += dd[k >> 2] * kw[k & 3];
    }
    // e=3: frag g=[8,16) uniform
    {
        const float4 ka = *reinterpret_cast<const float4*>(&wl[8]);
        const float4 kb = *reinterpret_cast<const float4*>(&wl[12]);
        const float kw[8] = {ka.x, ka.y, ka.z, ka.w, kb.x, kb.y, kb.z, kb.w};
        const float dd[2] = {d3.x, d3.y};
#pragma unroll
        for (int k = 0; k < 16; ++k)
            acc[k] += dd[k >> 3] * kw[k & 7];
    }
    // e=4: frag g=[16,32) uniform -> swz base 20, contiguous
    {
        const float4 f0 = *reinterpret_cast<const float4*>(&wl[20]);
        const float4 f1 = *reinterpret_cast<const float4*>(&wl[24]);
        const float4 f2 = *reinterpret_cast<const float4*>(&wl[28]);
        const float4 f3 = *reinterpret_cast<const float4*>(&wl[32]);
        const float c4 = cds[0];
        acc[0]  += c4 * f0.x; acc[1]  += c4 * f0.y; acc[2]  += c4 * f0.z; acc[3]  += c4 * f0.w;
        acc[4]  += c4 * f1.x; acc[5]  += c4 * f1.y; acc[6]  += c4 * f1.z; acc[7]  += c4 * f1.w;
        acc[8]  += c4 * f2.x; acc[9]  += c4 * f2.y; acc[10] += c4 * f2.z; acc[11] += c4 * f2.w;
        acc[12] += c4 * f3.x; acc[13] += c4 * f3.y; acc[14] += c4 * f3.z; acc[15] += c4 * f3.w;
    }
    // e=5..10: per-thread 16-float frag (16-aligned g0 -> contiguous in swz space)
#pragma unroll
    for (int e = 5; e <= 10; ++e) {
        const int g0 = (1 << e) + ((tid & ((1 << (e - 4)) - 1)) << 4);
        const int a0 = swz(g0);
        const float4 f0 = *reinterpret_cast<const float4*>(&wl[a0]);
        const float4 f1 = *reinterpret_cast<const float4*>(&wl[a0 + 4]);
        const float4 f2 = *reinterpret_cast<const float4*>(&wl[a0 + 8]);
        const float4 f3 = *reinterpret_cast<const float4*>(&wl[a0 + 12]);
        const float ce = cds[e - 4];
        acc[0]  += ce * f0.x; acc[1]  += ce * f0.y; acc[2]  += ce * f0.z; acc[3]  += ce * f0.w;
        acc[4]  += ce * f1.x; acc[5]  += ce * f1.y; acc[6]  += ce * f1.z; acc[7]  += ce * f1.w;
        acc[8]  += ce * f2.x; acc[9]  += ce * f2.y; acc[10] += ce * f2.z; acc[11] += ce * f2.w;
        acc[12] += ce * f3.x; acc[13] += ce * f3.y; acc[14] += ce * f3.z; acc[15] += ce * f3.w;
    }

    float4* o = reinterpret_cast<float4*>(out + (size_t)b * TSC_OUT_LEN + j0);
    o[0] = make_float4(acc[0],  acc[1],  acc[2],  acc[3]);
    o[1] = make_float4(acc[4],  acc[5],  acc[6],  acc[7]);
    o[2] = make_float4(acc[8],  acc[9],  acc[10], acc[11]);
    o[3] = make_float4(acc[12], acc[13], acc[14], acc[15]);
}

extern "C" void kernel_launch(void* const* d_in, const int* in_sizes, int n_in,
                              void* d_out, int out_size, void* d_ws, size_t ws_size,
                              hipStream_t stream) {
    const float* data    = (const float*)d_in[0];
    const float* weights = (const float*)d_in[1];
    const float* bias    = (const float*)d_in[2];
    float* out = (float*)d_out;

    const int B = in_sizes[0] / TSC_ENC_LEN;  // 2048
    dim3 grid(B * 2);                          // 2 half-row blocks per row
    dim3 block(512);
    tsc_transpose_kernel<<<grid, block, 0, stream>>>(data, weights, bias, out);
}